// Round 16
// baseline (195.143 us; speedup 1.0000x reference)
//
#include <hip/hip_runtime.h>
#include <cstdint>

// ---------------------------------------------------------------------------
// RotationScan: theta/retain/inp GEMM -> chunked complex scan -> out GEMM -> LN
// B=4 T=4096 D=1024 SD=512 CHUNK=32
// r16 = r15 + scan_k1/scan_k3 vectorized: each thread handles TWO adjacent
// d-values so all lin loads are ushort2 (4B/lane, 256B/wave full segment)
// and outb stores are ushort2. Math per element is order-identical to r15.
// ---------------------------------------------------------------------------

typedef __bf16 bf16x8 __attribute__((ext_vector_type(8)));
typedef float  f32x4  __attribute__((ext_vector_type(4)));
typedef ushort u16x8  __attribute__((ext_vector_type(8)));

#define AS1 __attribute__((address_space(1)))
#define AS3 __attribute__((address_space(3)))

__device__ __forceinline__ void gload16(const void* g, void* l) {
  __builtin_amdgcn_global_load_lds((const AS1 void*)g, (AS3 void*)l, 16, 0, 0);
}

__device__ __forceinline__ ushort f2bf(float f) {
  union { float f; uint32_t u; } v; v.f = f;
  uint32_t u = v.u;
  uint32_t r = u + 0x7FFFu + ((u >> 16) & 1u);   // RNE
  return (ushort)(r >> 16);
}
__device__ __forceinline__ float bf2f(ushort u) {
  union { uint32_t x; float f; } v; v.x = (uint32_t)u << 16; return v.f;
}
__device__ __forceinline__ u16x8 cvt8(float4 a, float4 b) {
  u16x8 o;
  o[0] = f2bf(a.x); o[1] = f2bf(a.y); o[2] = f2bf(a.z); o[3] = f2bf(a.w);
  o[4] = f2bf(b.x); o[5] = f2bf(b.y); o[6] = f2bf(b.z); o[7] = f2bf(b.w);
  return o;
}

// ---------------------------------------------------------------------------
// Fused transpose + f32->bf16 for all 4 weights (one launch).
// ---------------------------------------------------------------------------
__global__ __launch_bounds__(256) void tconv_all(const float* __restrict__ Wt,
                                                 const float* __restrict__ Wr,
                                                 const float* __restrict__ Wi,
                                                 const float* __restrict__ Wo,
                                                 ushort* __restrict__ wcat,
                                                 ushort* __restrict__ wot) {
  const int z = blockIdx.z;
  if (z < 2 && blockIdx.x >= 16) return;          // C=512 weights: 16 col-blocks
  const float* src = (z == 0) ? Wt : (z == 1) ? Wr : (z == 2) ? Wi : Wo;
  const int C = (z < 2) ? 512 : 1024;
  const int row_off = (z == 0) ? 0 : (z == 1) ? 512 : (z == 2) ? 1024 : 0;
  ushort* dst = (z == 3) ? wot : wcat;

  __shared__ float tile[32][33];
  int tx = threadIdx.x, ty = threadIdx.y;
  int rb = blockIdx.y * 32, cb = blockIdx.x * 32;
#pragma unroll
  for (int yy = 0; yy < 4; ++yy) {
    int r = rb + ty + yy * 8;
    tile[ty + yy * 8][tx] = src[(size_t)r * C + cb + tx];
  }
  __syncthreads();
#pragma unroll
  for (int yy = 0; yy < 4; ++yy) {
    int c = cb + ty + yy * 8;
    dst[(size_t)(row_off + c) * 1024 + rb + tx] = f2bf(tile[tx][ty + yy * 8]);
  }
}

__global__ __launch_bounds__(256) void pack_bias(const float* __restrict__ bt,
                                                 const float* __restrict__ br,
                                                 const float* __restrict__ bi,
                                                 float* __restrict__ bcat) {
  int i = blockIdx.x * 256 + threadIdx.x;          // 0..2047
  bcat[i] = (i < 512) ? bt[i] : (i < 1024 ? br[i - 512] : bi[i - 1024]);
}

// ---------------------------------------------------------------------------
// 256x256 tile, BK=64, 8 waves (2Mx4N), double-buffered 128 KiB LDS.
// 16x16x32 MFMA + chunk^(row&7) swizzle (verified conflict-free).
// r11/r13 schedule (session-best): single publish vmcnt per K-tile, QUAD2
// pre-read before the WAR-spacer barrier.
//
// AF32=false (GEMM2): 8 gload_lds/K-tile, P0 wait vmcnt(2) [tail 0].
// AF32=true (GEMM1): A reg-staged from f32, 1-tile-deep prefetch:
//   P0 wait vmcnt(10) lgkmcnt(0); P2/P3: AWRITE(kt+1) then ALOAD(kt+2).
//
// Epilogue: C-tile -> LDS 16B-chunk XOR swizzle -> coalesced u16x8 stores.
// resid != nullptr (GEMM2): depth-4 rolling-prefetch coalesced f32 residual.
// ---------------------------------------------------------------------------
template <bool AF32>
__global__ __launch_bounds__(512, 2) void gemm256(const void* __restrict__ Aptr,
                                                  const ushort* __restrict__ Bt,
                                                  ushort* __restrict__ C,
                                                  const float* __restrict__ bias,
                                                  const float* __restrict__ resid,
                                                  int M, int N, int K, int nbn) {
  __shared__ alignas(16) ushort smem[65536];      // stage 128KB == C-tile 128KB
  ushort* const As0 = smem;
  ushort* const Bs0 = smem + 2 * 256 * 64;

  const int cpx = gridDim.x >> 3;
  const int wg = ((int)blockIdx.x & 7) * cpx + ((int)blockIdx.x >> 3);
  const int bm = wg / nbn, bn = wg % nbn;

  const int t = threadIdx.x;
  const int l = t & 63, w = t >> 6;
  const int wm = w >> 2, wn = w & 3;
  const int r = l & 15, kq = l >> 4;

  const size_t a0 = (size_t)bm * 256 * K;
  const size_t b0 = (size_t)bn * 256 * K;

  const int srow = t >> 3;
  const int sslot = (t & 7) ^ (srow & 7);
  const ushort* gA16 = (const ushort*)Aptr + a0 + (size_t)srow * K + sslot * 8;
  const float*  gAf  = (const float*)Aptr + a0 + (size_t)srow * K + sslot * 8;
  const ushort* gB = Bt + b0 + (size_t)srow * K + sslot * 8;
  const int lboff = w * 1024 + l * 16;

  f32x4 acc[8][4] = {};
  const int NKT = K >> 6;
  float4 areg[4][2];

#define STGA(buf, kt, u) \
  gload16(gA16 + (size_t)((u) * 64) * K + (size_t)(kt) * 64, \
          (char*)(As0 + (buf) * 256 * 64) + (u) * 8192 + lboff)
#define STGB(buf, kt, u) \
  gload16(gB + (size_t)((u) * 64) * K + (size_t)(kt) * 64, \
          (char*)(Bs0 + (buf) * 256 * 64) + (u) * 8192 + lboff)
#define ALOAD(kt, u) \
  do { const float* gs_ = gAf + (size_t)((u) * 64) * K + (size_t)(kt) * 64; \
       areg[u][0] = *(const float4*)gs_; areg[u][1] = *(const float4*)(gs_ + 4); } while (0)
#define AWRITE(buf, u) \
  *(u16x8*)((char*)(As0 + (buf) * 256 * 64) + (u) * 8192 + lboff) = cvt8(areg[u][0], areg[u][1])

#define QUAD(ph)                                                               \
  do {                                                                         \
    _Pragma("unroll")                                                          \
    for (int ii = 0; ii < 2; ++ii) {                                           \
      bf16x8 aF[2];                                                            \
      const int rowa = wm * 128 + ((ph) * 2 + ii) * 16 + r;                    \
      _Pragma("unroll")                                                        \
      for (int ks = 0; ks < 2; ++ks) {                                         \
        const int j = (ks * 4 + kq) ^ (r & 7);                                 \
        aF[ks] = *(const bf16x8*)&pA[rowa * 64 + j * 8];                       \
      }                                                                        \
      __builtin_amdgcn_s_setprio(1);                                           \
      _Pragma("unroll")                                                        \
      for (int jn = 0; jn < 4; ++jn)                                           \
        _Pragma("unroll")                                                      \
        for (int ks = 0; ks < 2; ++ks)                                         \
          acc[(ph) * 2 + ii][jn] = __builtin_amdgcn_mfma_f32_16x16x32_bf16(    \
              aF[ks], bF[jn][ks], acc[(ph) * 2 + ii][jn], 0, 0, 0);            \
      __builtin_amdgcn_s_setprio(0);                                           \
    }                                                                          \
  } while (0)

  if constexpr (AF32) {
#pragma unroll
    for (int u = 0; u < 4; ++u) ALOAD(0, u);
    STGB(0, 0, 0); STGB(0, 0, 1); STGB(0, 0, 2); STGB(0, 0, 3);
#pragma unroll
    for (int u = 0; u < 4; ++u) AWRITE(0, u);
    if (NKT > 1) {
#pragma unroll
      for (int u = 0; u < 4; ++u) ALOAD(1, u);
    }
  } else {
    STGB(0, 0, 0); STGB(0, 0, 1); STGB(0, 0, 2); STGB(0, 0, 3);
    STGA(0, 0, 0); STGA(0, 0, 2); STGA(0, 0, 1); STGA(0, 0, 3);
  }

  for (int kt = 0; kt < NKT; ++kt) {
    const int cur = kt & 1, nxt = cur ^ 1;
    const bool hn = (kt + 1 < NKT);
    const ushort* pA = As0 + cur * 256 * 64;
    const ushort* pB = Bs0 + cur * 256 * 64;

    // ---------------- phase 0 (publish) ----------------
    if (hn) { STGB(nxt, kt + 1, 0); STGB(nxt, kt + 1, 1); }
    if constexpr (AF32) {
      if (hn) asm volatile("s_waitcnt vmcnt(10) lgkmcnt(0)" ::: "memory");
      else    asm volatile("s_waitcnt vmcnt(0) lgkmcnt(0)" ::: "memory");
    } else {
      if (hn) asm volatile("s_waitcnt vmcnt(2)" ::: "memory");
      else    asm volatile("s_waitcnt vmcnt(0)" ::: "memory");
    }
    __builtin_amdgcn_s_barrier();
    asm volatile("" ::: "memory");
    bf16x8 bF[4][2];
#pragma unroll
    for (int jn = 0; jn < 4; ++jn) {
      const int rowb = wn * 64 + jn * 16 + r;
#pragma unroll
      for (int ks = 0; ks < 2; ++ks) {
        const int j = (ks * 4 + kq) ^ (r & 7);
        bF[jn][ks] = *(const bf16x8*)&pB[rowb * 64 + j * 8];
      }
    }
    QUAD(0);
    // ---------------- phase 1 ----------------
    if (hn) { STGB(nxt, kt + 1, 2); STGB(nxt, kt + 1, 3); }
    QUAD(1);
    // pre-read phase-2 fragments (As[cur] published at P0 barrier -> legal)
    bf16x8 aFn[2][2];
#pragma unroll
    for (int ii = 0; ii < 2; ++ii) {
      const int rowa = wm * 128 + (4 + ii) * 16 + r;
#pragma unroll
      for (int ks = 0; ks < 2; ++ks) {
        const int j = (ks * 4 + kq) ^ (r & 7);
        aFn[ii][ks] = *(const bf16x8*)&pA[rowa * 64 + j * 8];
      }
    }
    // ---------------- phase 2 (WAR spacer) ----------------
    if constexpr (AF32) {
      if (hn) { AWRITE(nxt, 0); AWRITE(nxt, 1); }
      if (kt + 2 < NKT) { ALOAD(kt + 2, 0); ALOAD(kt + 2, 1); }
    } else {
      if (hn) { STGA(nxt, kt + 1, 0); STGA(nxt, kt + 1, 2); }
    }
    asm volatile("" ::: "memory");
    __builtin_amdgcn_s_barrier();
    __builtin_amdgcn_s_setprio(1);
#pragma unroll
    for (int ii = 0; ii < 2; ++ii)
#pragma unroll
      for (int jn = 0; jn < 4; ++jn)
#pragma unroll
        for (int ks = 0; ks < 2; ++ks)
          acc[4 + ii][jn] = __builtin_amdgcn_mfma_f32_16x16x32_bf16(
              aFn[ii][ks], bF[jn][ks], acc[4 + ii][jn], 0, 0, 0);
    __builtin_amdgcn_s_setprio(0);
    // ---------------- phase 3 ----------------
    if constexpr (AF32) {
      if (hn) { AWRITE(nxt, 2); AWRITE(nxt, 3); }
      if (kt + 2 < NKT) { ALOAD(kt + 2, 2); ALOAD(kt + 2, 3); }
    } else {
      if (hn) { STGA(nxt, kt + 1, 1); STGA(nxt, kt + 1, 3); }
    }
    QUAD(3);
  }
#undef STGA
#undef STGB
#undef ALOAD
#undef AWRITE
#undef QUAD

  // ---- epilogue via LDS: swizzled scatter, then coalesced 16B stores ----
  asm volatile("s_waitcnt lgkmcnt(0) vmcnt(0)" ::: "memory");
  __builtin_amdgcn_s_barrier();                   // all waves done with stage LDS

  const int q4 = (l >> 4) * 4;
  float bvj[4];
#pragma unroll
  for (int jn = 0; jn < 4; ++jn) {
    const int col = wn * 64 + jn * 16 + r;
    bvj[jn] = bias ? bias[bn * 256 + col] : 0.f;
  }
#pragma unroll
  for (int i = 0; i < 8; ++i) {
#pragma unroll
    for (int jn = 0; jn < 4; ++jn) {
      const int col = wn * 64 + jn * 16 + r;
      const int chunk = col >> 3;
#pragma unroll
      for (int q = 0; q < 4; ++q) {
        const int rowl = wm * 128 + i * 16 + q4 + q;
        const int pch = chunk ^ (rowl & 7);
        smem[rowl * 256 + pch * 8 + (col & 7)] = f2bf(acc[i][jn][q] + bvj[jn]);
      }
    }
  }
  __builtin_amdgcn_s_barrier();

  const int rrow0 = t >> 5;                       // 0..15
  const int rch = t & 31;                         // logical 16B chunk
  if (resid == nullptr) {
#pragma unroll
    for (int p = 0; p < 16; ++p) {
      const int rowl = p * 16 + rrow0;
      const int pch = rch ^ (rowl & 7);
      u16x8 vv = *(const u16x8*)&smem[rowl * 256 + pch * 8];
      const size_t grow = (size_t)(bm * 256 + rowl);
      *(u16x8*)&C[grow * N + bn * 256 + rch * 8] = vv;
    }
  } else {
    // depth-4 rolling prefetch of the residual (static indices: full unroll)
    f32x4 xa[4][2];
#pragma unroll
    for (int pp = 0; pp < 3; ++pp) {
      const int rowl = pp * 16 + rrow0;
      const float* xp = resid + (size_t)(bm * 256 + rowl) * N + bn * 256 + rch * 8;
      xa[pp][0] = *(const f32x4*)xp;
      xa[pp][1] = *(const f32x4*)(xp + 4);
    }
#pragma unroll
    for (int p = 0; p < 16; ++p) {
      if (p + 3 < 16) {
        const int rowl = (p + 3) * 16 + rrow0;
        const float* xp = resid + (size_t)(bm * 256 + rowl) * N + bn * 256 + rch * 8;
        xa[(p + 3) & 3][0] = *(const f32x4*)xp;
        xa[(p + 3) & 3][1] = *(const f32x4*)(xp + 4);
      }
      const int rowl = p * 16 + rrow0;
      const int pch = rch ^ (rowl & 7);
      u16x8 vv = *(const u16x8*)&smem[rowl * 256 + pch * 8];
      u16x8 ov;
#pragma unroll
      for (int j = 0; j < 4; ++j) ov[j] = f2bf(bf2f(vv[j]) + xa[p & 3][0][j]);
#pragma unroll
      for (int j = 0; j < 4; ++j) ov[4 + j] = f2bf(bf2f(vv[4 + j]) + xa[p & 3][1][j]);
      const size_t grow = (size_t)(bm * 256 + rowl);
      *(u16x8*)&C[grow * N + bn * 256 + rch * 8] = ov;
    }
  }
}

// ---------------------------------------------------------------------------
// Scan kernels. lin[row, 2048] (bf16): [theta | retain_logit | inp_r | inp_i]
// Vectorized: each thread handles TWO adjacent d-values -> all lin loads are
// ushort2 (4B/lane, 256B/wave). Per-element math order-identical to r15.
// ---------------------------------------------------------------------------
__global__ __launch_bounds__(256) void scan_k1(const ushort* __restrict__ lin,
                                               float4* __restrict__ agg) {
  int bd2 = blockIdx.x * 256 + threadIdx.x;   // 0..1023  (b*256 + dpair)
  int c  = blockIdx.y;                         // 0..127
  int b  = bd2 >> 8, d0 = (bd2 & 255) * 2;
  const ushort* base = lin + ((size_t)b * 4096 + (size_t)c * 32) * 2048;
  float cth[2] = {0.f, 0.f}, cbr[2] = {0.f, 0.f}, cbi[2] = {0.f, 0.f};
  float cm[2] = {1.f, 1.f}, cs[2] = {1.f, 1.f}, sn[2] = {0.f, 0.f};
#pragma unroll 4
  for (int t = 0; t < 32; ++t) {
    const ushort* row = base + (size_t)t * 2048;
    ushort2 th2 = *(const ushort2*)(row + d0);
    ushort2 z2  = *(const ushort2*)(row + 512 + d0);
    ushort2 ir2 = *(const ushort2*)(row + 1024 + d0);
    ushort2 ii2 = *(const ushort2*)(row + 1536 + d0);
#pragma unroll
    for (int j = 0; j < 2; ++j) {
      float th = bf2f(j ? th2.y : th2.x);
      float z  = bf2f(j ? z2.y  : z2.x);
      float ir = bf2f(j ? ir2.y : ir2.x);
      float ii = bf2f(j ? ii2.y : ii2.x);
      float rt = __fdividef(1.f, 1.f + __expf(-z));
      cm[j] *= fmaxf(rt, 1e-6f);
      cth[j] += th;
      float s_, c_;
      __sincosf(cth[j], &s_, &c_);
      float im = __fdividef(1.f, fmaxf(cm[j], 1e-8f));
      float invr = im * c_, invi = -im * s_;
      float drive = 1.f - rt;
      float br_ = drive * ir, bi_ = drive * ii;
      cbr[j] += invr * br_ - invi * bi_;
      cbi[j] += invr * bi_ + invi * br_;
      cs[j] = c_; sn[j] = s_;
    }
  }
  size_t o = (size_t)c * 2048 + (size_t)b * 512 + d0;
  agg[o]     = make_float4(cm[0] * cs[0], cm[0] * sn[0], cbr[0], cbi[0]);
  agg[o + 1] = make_float4(cm[1] * cs[1], cm[1] * sn[1], cbr[1], cbi[1]);
}

__global__ __launch_bounds__(256) void scan_k2(const float4* __restrict__ agg,
                                               float2* __restrict__ h0) {
  int bd = blockIdx.x * 256 + threadIdx.x;    // 2048 threads
  float hr = 0.f, hi = 0.f;
  for (int cg = 0; cg < 16; ++cg) {
    float4 a[8];
#pragma unroll
    for (int u = 0; u < 8; ++u) a[u] = agg[(size_t)(cg * 8 + u) * 2048 + bd];
#pragma unroll
    for (int u = 0; u < 8; ++u) {
      h0[(size_t)(cg * 8 + u) * 2048 + bd] = make_float2(hr, hi);
      float tr = hr + a[u].z, ti = hi + a[u].w;
      hr = a[u].x * tr - a[u].y * ti;
      hi = a[u].x * ti + a[u].y * tr;
    }
  }
}

__global__ __launch_bounds__(256) void scan_k3(const ushort* __restrict__ lin,
                                               const float2* __restrict__ h0,
                                               ushort* __restrict__ outb) {
  int bd2 = blockIdx.x * 256 + threadIdx.x;   // 0..1023  (b*256 + dpair)
  int c  = blockIdx.y;
  int b  = bd2 >> 8, d0 = (bd2 & 255) * 2;
  const ushort* base = lin + ((size_t)b * 4096 + (size_t)c * 32) * 2048;
  size_t ho = (size_t)c * 2048 + (size_t)b * 512 + d0;
  float2 h0v = h0[ho];
  float2 h1v = h0[ho + 1];
  float hx[2] = {h0v.x, h1v.x}, hy[2] = {h0v.y, h1v.y};
  float cth[2] = {0.f, 0.f}, cbr[2] = {0.f, 0.f}, cbi[2] = {0.f, 0.f};
  float cm[2] = {1.f, 1.f};
#pragma unroll 4
  for (int t = 0; t < 32; ++t) {
    const ushort* row = base + (size_t)t * 2048;
    ushort2 th2 = *(const ushort2*)(row + d0);
    ushort2 z2  = *(const ushort2*)(row + 512 + d0);
    ushort2 ir2 = *(const ushort2*)(row + 1024 + d0);
    ushort2 ii2 = *(const ushort2*)(row + 1536 + d0);
    ushort orr2[2], oii2[2];
#pragma unroll
    for (int j = 0; j < 2; ++j) {
      float th = bf2f(j ? th2.y : th2.x);
      float z  = bf2f(j ? z2.y  : z2.x);
      float ir = bf2f(j ? ir2.y : ir2.x);
      float ii = bf2f(j ? ii2.y : ii2.x);
      float rt = __fdividef(1.f, 1.f + __expf(-z));
      cm[j] *= fmaxf(rt, 1e-6f);
      cth[j] += th;
      float s_, c_;
      __sincosf(cth[j], &s_, &c_);
      float im = __fdividef(1.f, fmaxf(cm[j], 1e-8f));
      float invr = im * c_, invi = -im * s_;
      float drive = 1.f - rt;
      float br_ = drive * ir, bi_ = drive * ii;
      cbr[j] += invr * br_ - invi * bi_;
      cbi[j] += invr * bi_ + invi * br_;
      float ar = cm[j] * c_, ai = cm[j] * s_;
      float tr = hx[j] + cbr[j], ti = hy[j] + cbi[j];
      orr2[j] = f2bf(ar * tr - ai * ti);
      oii2[j] = f2bf(ar * ti + ai * tr);
    }
    size_t rowo = ((size_t)b * 4096 + (size_t)c * 32 + t) * 1024;
    ushort2 vr; vr.x = orr2[0]; vr.y = orr2[1];
    ushort2 vi; vi.x = oii2[0]; vi.y = oii2[1];
    *(ushort2*)(outb + rowo + d0) = vr;
    *(ushort2*)(outb + rowo + 512 + d0) = vi;
  }
}

// ---------------------------------------------------------------------------
// LayerNorm, one WAVE per row (4 rows/block). yb already includes residual.
// ---------------------------------------------------------------------------
__global__ __launch_bounds__(256) void ln_k(const ushort* __restrict__ yb,
                                            const float* __restrict__ gamma,
                                            const float* __restrict__ beta,
                                            float* __restrict__ out) {
  const int lane = threadIdx.x & 63;
  const size_t row = (size_t)blockIdx.x * 4 + (threadIdx.x >> 6);
  const ushort* yr = yb + row * 1024;
  float v[4][4];
  float s = 0.f, s2 = 0.f;
#pragma unroll
  for (int q = 0; q < 4; ++q) {
    ushort4 uy = *(const ushort4*)(yr + q * 256 + lane * 4);
    v[q][0] = bf2f(uy.x);
    v[q][1] = bf2f(uy.y);
    v[q][2] = bf2f(uy.z);
    v[q][3] = bf2f(uy.w);
#pragma unroll
    for (int j = 0; j < 4; ++j) { s += v[q][j]; s2 += v[q][j] * v[q][j]; }
  }
#pragma unroll
  for (int off = 32; off > 0; off >>= 1) {
    s  += __shfl_xor(s, off);
    s2 += __shfl_xor(s2, off);
  }
  const float mu = s * (1.f / 1024.f);
  const float rstd = rsqrtf(s2 * (1.f / 1024.f) - mu * mu + 1e-5f);
#pragma unroll
  for (int q = 0; q < 4; ++q) {
    float4 gv = *(const float4*)(gamma + q * 256 + lane * 4);
    float4 bv = *(const float4*)(beta + q * 256 + lane * 4);
    float4 o;
    o.x = (v[q][0] - mu) * rstd * gv.x + bv.x;
    o.y = (v[q][1] - mu) * rstd * gv.y + bv.y;
    o.z = (v[q][2] - mu) * rstd * gv.z + bv.z;
    o.w = (v[q][3] - mu) * rstd * gv.w + bv.w;
    *(float4*)(out + row * 1024 + q * 256 + lane * 4) = o;
  }
}

// ---------------------------------------------------------------------------
extern "C" void kernel_launch(void* const* d_in, const int* in_sizes, int n_in,
                              void* d_out, int out_size, void* d_ws, size_t ws_size,
                              hipStream_t stream) {
  (void)in_sizes; (void)n_in; (void)out_size; (void)ws_size;
  const float* x  = (const float*)d_in[0];
  const float* Wt = (const float*)d_in[1];
  const float* bt = (const float*)d_in[2];
  const float* Wr = (const float*)d_in[3];
  const float* br = (const float*)d_in[4];
  const float* Wi = (const float*)d_in[5];
  const float* bi = (const float*)d_in[6];
  const float* Wo = (const float*)d_in[7];
  const float* bo = (const float*)d_in[8];
  const float* gamma = (const float*)d_in[9];
  const float* beta  = (const float*)d_in[10];

  char* ws = (char*)d_ws;
  ushort* wcat_t = (ushort*)(ws);                      //  4 MiB: [2048][1024] bf16
  ushort* wo_t   = (ushort*)(ws + ((size_t)4  << 20)); //  2 MiB: [1024][1024] bf16
  float*  bcat   = (float*) (ws + ((size_t)6  << 20)); //  8 KiB
  float4* agg    = (float4*)(ws + ((size_t)8  << 20)); //  4 MiB: [128][2048]
  float2* h0     = (float2*)(ws + ((size_t)12 << 20)); //  2 MiB: [128][2048]
  ushort* outb   = (ushort*)(ws + ((size_t)48 << 20)); // 32 MiB: scan out bf16
  ushort* linb   = (ushort*)(ws + ((size_t)80 << 20)); // 64 MiB: lin bf16
  ushort* yb     = (ushort*)(ws + ((size_t)80 << 20)); // 32 MiB: y bf16 (overlays dead linb)

  // weight prep (fused) + bias pack
  tconv_all<<<dim3(32, 32, 4), dim3(32, 8), 0, stream>>>(Wt, Wr, Wi, Wo, wcat_t, wo_t);
  pack_bias<<<8, 256, 0, stream>>>(bt, br, bi, bcat);

  // lin(bf16) = x(f32, converted in-kernel) @ [Wt|Wr|Wi] + [bt|br|bi]
  gemm256<true><<<512, 512, 0, stream>>>(x, wcat_t, linb, bcat, nullptr,
                                         16384, 2048, 1024, 8);

  // chunked complex scan (vectorized ushort2 loads, 2 d-values per thread)
  scan_k1<<<dim3(4, 128), 256, 0, stream>>>(linb, agg);
  scan_k2<<<8, 256, 0, stream>>>(agg, h0);
  scan_k3<<<dim3(4, 128), 256, 0, stream>>>(linb, h0, outb);

  // yb(bf16) = out @ Wo + bo + x   (residual fused into epilogue; 256 blocks)
  gemm256<false><<<256, 512, 0, stream>>>(outb, wo_t, yb, bo, x,
                                          16384, 1024, 1024, 4);

  // layernorm(yb) -> d_out   (one wave per row; yb already has residual)
  ln_k<<<4096, 256, 0, stream>>>(yb, gamma, beta, (float*)d_out);
}

// Round 17
// 193.355 us; speedup vs baseline: 1.0093x; 1.0093x over previous
//
#include <hip/hip_runtime.h>
#include <cstdint>

// ---------------------------------------------------------------------------
// RotationScan: theta/retain/inp GEMM -> chunked complex scan -> out GEMM -> LN
// B=4 T=4096 D=1024 SD=512 CHUNK=32
// r17 = r13 verbatim (session-best 193.45us). Final configuration:
//  - GEMM1: 256x256 BK=64 8-wave, A reg-staged f32->bf16 with 1-tile-deep
//    prefetch, single-publish counted-vmcnt schedule, LDS-staged epilogue.
//  - GEMM2: same kernel, gload_lds A path, 256 blocks (1/CU).
//  - 3-kernel chunked scan (reference clip semantics), waveized LN.
// Plateau notes: 7 GEMM schedule structures land at ~870 TF (MfmaUtil ~35%);
// scan/LN within noise of traffic floor. Session: 306 -> 193.5us.
// ---------------------------------------------------------------------------

typedef __bf16 bf16x8 __attribute__((ext_vector_type(8)));
typedef float  f32x4  __attribute__((ext_vector_type(4)));
typedef ushort u16x8  __attribute__((ext_vector_type(8)));

#define AS1 __attribute__((address_space(1)))
#define AS3 __attribute__((address_space(3)))

__device__ __forceinline__ void gload16(const void* g, void* l) {
  __builtin_amdgcn_global_load_lds((const AS1 void*)g, (AS3 void*)l, 16, 0, 0);
}

__device__ __forceinline__ ushort f2bf(float f) {
  union { float f; uint32_t u; } v; v.f = f;
  uint32_t u = v.u;
  uint32_t r = u + 0x7FFFu + ((u >> 16) & 1u);   // RNE
  return (ushort)(r >> 16);
}
__device__ __forceinline__ float bf2f(ushort u) {
  union { uint32_t x; float f; } v; v.x = (uint32_t)u << 16; return v.f;
}
__device__ __forceinline__ u16x8 cvt8(float4 a, float4 b) {
  u16x8 o;
  o[0] = f2bf(a.x); o[1] = f2bf(a.y); o[2] = f2bf(a.z); o[3] = f2bf(a.w);
  o[4] = f2bf(b.x); o[5] = f2bf(b.y); o[6] = f2bf(b.z); o[7] = f2bf(b.w);
  return o;
}

// ---------------------------------------------------------------------------
// Fused transpose + f32->bf16 for all 4 weights (one launch).
// ---------------------------------------------------------------------------
__global__ __launch_bounds__(256) void tconv_all(const float* __restrict__ Wt,
                                                 const float* __restrict__ Wr,
                                                 const float* __restrict__ Wi,
                                                 const float* __restrict__ Wo,
                                                 ushort* __restrict__ wcat,
                                                 ushort* __restrict__ wot) {
  const int z = blockIdx.z;
  if (z < 2 && blockIdx.x >= 16) return;          // C=512 weights: 16 col-blocks
  const float* src = (z == 0) ? Wt : (z == 1) ? Wr : (z == 2) ? Wi : Wo;
  const int C = (z < 2) ? 512 : 1024;
  const int row_off = (z == 0) ? 0 : (z == 1) ? 512 : (z == 2) ? 1024 : 0;
  ushort* dst = (z == 3) ? wot : wcat;

  __shared__ float tile[32][33];
  int tx = threadIdx.x, ty = threadIdx.y;
  int rb = blockIdx.y * 32, cb = blockIdx.x * 32;
#pragma unroll
  for (int yy = 0; yy < 4; ++yy) {
    int r = rb + ty + yy * 8;
    tile[ty + yy * 8][tx] = src[(size_t)r * C + cb + tx];
  }
  __syncthreads();
#pragma unroll
  for (int yy = 0; yy < 4; ++yy) {
    int c = cb + ty + yy * 8;
    dst[(size_t)(row_off + c) * 1024 + rb + tx] = f2bf(tile[tx][ty + yy * 8]);
  }
}

__global__ __launch_bounds__(256) void pack_bias(const float* __restrict__ bt,
                                                 const float* __restrict__ br,
                                                 const float* __restrict__ bi,
                                                 float* __restrict__ bcat) {
  int i = blockIdx.x * 256 + threadIdx.x;          // 0..2047
  bcat[i] = (i < 512) ? bt[i] : (i < 1024 ? br[i - 512] : bi[i - 1024]);
}

// ---------------------------------------------------------------------------
// 256x256 tile, BK=64, 8 waves (2Mx4N), double-buffered 128 KiB LDS.
// 16x16x32 MFMA + chunk^(row&7) swizzle (verified conflict-free).
//
// AF32=false (GEMM2): 8 gload_lds/K-tile, P0 wait vmcnt(2) [tail 0],
//   P2 WAR-spacer barrier, QUAD2 pre-read.
// AF32=true (GEMM1): A reg-staged from f32 with ONE-TILE-DEEP prefetch:
//   P0: stage B0,B1(kt+1); wait vmcnt(10) lgkmcnt(0) [tail vmcnt(0)]:
//       newest 10 = {B0B1(kt+1), A(kt+1) 8 loads from P2/P3(kt-1)} ->
//       B(kt) fully landed; lgkmcnt publishes kt-1's A ds_writes; barrier.
//   P1: stage B2,B3(kt+1); QUAD1; pre-read aF q2.
//   P2: AWRITE(nxt, p0,p1) [consumes A(kt+1), 4-phase slack];
//       ALOAD(kt+2, p0,p1); clobber+barrier (WAR spacer); MFMA q2.
//   P3: AWRITE(nxt, p2,p3); ALOAD(kt+2, p2,p3); QUAD3.
// Epilogue: C-tile -> LDS 16B-chunk XOR swizzle -> coalesced u16x8 stores
// (WRITE_SIZE == output bytes, no RMW).
// ---------------------------------------------------------------------------
template <bool AF32>
__global__ __launch_bounds__(512, 2) void gemm256(const void* __restrict__ Aptr,
                                                  const ushort* __restrict__ Bt,
                                                  ushort* __restrict__ C,
                                                  const float* __restrict__ bias,
                                                  int M, int N, int K, int nbn) {
  __shared__ alignas(16) ushort smem[65536];      // stage 128KB == C-tile 128KB
  ushort* const As0 = smem;
  ushort* const Bs0 = smem + 2 * 256 * 64;

  const int cpx = gridDim.x >> 3;
  const int wg = ((int)blockIdx.x & 7) * cpx + ((int)blockIdx.x >> 3);
  const int bm = wg / nbn, bn = wg % nbn;

  const int t = threadIdx.x;
  const int l = t & 63, w = t >> 6;
  const int wm = w >> 2, wn = w & 3;
  const int r = l & 15, kq = l >> 4;

  const size_t a0 = (size_t)bm * 256 * K;
  const size_t b0 = (size_t)bn * 256 * K;

  const int srow = t >> 3;
  const int sslot = (t & 7) ^ (srow & 7);
  const ushort* gA16 = (const ushort*)Aptr + a0 + (size_t)srow * K + sslot * 8;
  const float*  gAf  = (const float*)Aptr + a0 + (size_t)srow * K + sslot * 8;
  const ushort* gB = Bt + b0 + (size_t)srow * K + sslot * 8;
  const int lboff = w * 1024 + l * 16;

  f32x4 acc[8][4] = {};
  const int NKT = K >> 6;
  float4 areg[4][2];

#define STGA(buf, kt, u) \
  gload16(gA16 + (size_t)((u) * 64) * K + (size_t)(kt) * 64, \
          (char*)(As0 + (buf) * 256 * 64) + (u) * 8192 + lboff)
#define STGB(buf, kt, u) \
  gload16(gB + (size_t)((u) * 64) * K + (size_t)(kt) * 64, \
          (char*)(Bs0 + (buf) * 256 * 64) + (u) * 8192 + lboff)
#define ALOAD(kt, u) \
  do { const float* gs_ = gAf + (size_t)((u) * 64) * K + (size_t)(kt) * 64; \
       areg[u][0] = *(const float4*)gs_; areg[u][1] = *(const float4*)(gs_ + 4); } while (0)
#define AWRITE(buf, u) \
  *(u16x8*)((char*)(As0 + (buf) * 256 * 64) + (u) * 8192 + lboff) = cvt8(areg[u][0], areg[u][1])

#define QUAD(ph)                                                               \
  do {                                                                         \
    _Pragma("unroll")                                                          \
    for (int ii = 0; ii < 2; ++ii) {                                           \
      bf16x8 aF[2];                                                            \
      const int rowa = wm * 128 + ((ph) * 2 + ii) * 16 + r;                    \
      _Pragma("unroll")                                                        \
      for (int ks = 0; ks < 2; ++ks) {                                         \
        const int j = (ks * 4 + kq) ^ (r & 7);                                 \
        aF[ks] = *(const bf16x8*)&pA[rowa * 64 + j * 8];                       \
      }                                                                        \
      __builtin_amdgcn_s_setprio(1);                                           \
      _Pragma("unroll")                                                        \
      for (int jn = 0; jn < 4; ++jn)                                           \
        _Pragma("unroll")                                                      \
        for (int ks = 0; ks < 2; ++ks)                                         \
          acc[(ph) * 2 + ii][jn] = __builtin_amdgcn_mfma_f32_16x16x32_bf16(    \
              aF[ks], bF[jn][ks], acc[(ph) * 2 + ii][jn], 0, 0, 0);            \
      __builtin_amdgcn_s_setprio(0);                                           \
    }                                                                          \
  } while (0)

  // prologue
  if constexpr (AF32) {
#pragma unroll
    for (int u = 0; u < 4; ++u) ALOAD(0, u);      // A(0) loads (oldest)
    STGB(0, 0, 0); STGB(0, 0, 1); STGB(0, 0, 2); STGB(0, 0, 3);
#pragma unroll
    for (int u = 0; u < 4; ++u) AWRITE(0, u);     // compiler waits A(0) loads
    if (NKT > 1) {
#pragma unroll
      for (int u = 0; u < 4; ++u) ALOAD(1, u);    // prefetch tile 1
    }
  } else {
    STGB(0, 0, 0); STGB(0, 0, 1); STGB(0, 0, 2); STGB(0, 0, 3);
    STGA(0, 0, 0); STGA(0, 0, 2); STGA(0, 0, 1); STGA(0, 0, 3);
  }

  for (int kt = 0; kt < NKT; ++kt) {
    const int cur = kt & 1, nxt = cur ^ 1;
    const bool hn = (kt + 1 < NKT);
    const ushort* pA = As0 + cur * 256 * 64;
    const ushort* pB = Bs0 + cur * 256 * 64;

    // ---------------- phase 0 (publish) ----------------
    if (hn) { STGB(nxt, kt + 1, 0); STGB(nxt, kt + 1, 1); }
    if constexpr (AF32) {
      if (hn) asm volatile("s_waitcnt vmcnt(10) lgkmcnt(0)" ::: "memory");
      else    asm volatile("s_waitcnt vmcnt(0) lgkmcnt(0)" ::: "memory");
    } else {
      if (hn) asm volatile("s_waitcnt vmcnt(2)" ::: "memory");
      else    asm volatile("s_waitcnt vmcnt(0)" ::: "memory");
    }
    __builtin_amdgcn_s_barrier();
    asm volatile("" ::: "memory");
    bf16x8 bF[4][2];
#pragma unroll
    for (int jn = 0; jn < 4; ++jn) {
      const int rowb = wn * 64 + jn * 16 + r;
#pragma unroll
      for (int ks = 0; ks < 2; ++ks) {
        const int j = (ks * 4 + kq) ^ (r & 7);
        bF[jn][ks] = *(const bf16x8*)&pB[rowb * 64 + j * 8];
      }
    }
    QUAD(0);
    // ---------------- phase 1 ----------------
    if (hn) { STGB(nxt, kt + 1, 2); STGB(nxt, kt + 1, 3); }
    QUAD(1);
    // pre-read phase-2 fragments (As[cur] published at P0 barrier -> legal)
    bf16x8 aFn[2][2];
#pragma unroll
    for (int ii = 0; ii < 2; ++ii) {
      const int rowa = wm * 128 + (4 + ii) * 16 + r;
#pragma unroll
      for (int ks = 0; ks < 2; ++ks) {
        const int j = (ks * 4 + kq) ^ (r & 7);
        aFn[ii][ks] = *(const bf16x8*)&pA[rowa * 64 + j * 8];
      }
    }
    // ---------------- phase 2 (WAR spacer) ----------------
    if constexpr (AF32) {
      if (hn) { AWRITE(nxt, 0); AWRITE(nxt, 1); }
      if (kt + 2 < NKT) { ALOAD(kt + 2, 0); ALOAD(kt + 2, 1); }
    } else {
      if (hn) { STGA(nxt, kt + 1, 0); STGA(nxt, kt + 1, 2); }
    }
    asm volatile("" ::: "memory");
    __builtin_amdgcn_s_barrier();
    __builtin_amdgcn_s_setprio(1);
#pragma unroll
    for (int ii = 0; ii < 2; ++ii)
#pragma unroll
      for (int jn = 0; jn < 4; ++jn)
#pragma unroll
        for (int ks = 0; ks < 2; ++ks)
          acc[4 + ii][jn] = __builtin_amdgcn_mfma_f32_16x16x32_bf16(
              aFn[ii][ks], bF[jn][ks], acc[4 + ii][jn], 0, 0, 0);
    __builtin_amdgcn_s_setprio(0);
    // ---------------- phase 3 ----------------
    if constexpr (AF32) {
      if (hn) { AWRITE(nxt, 2); AWRITE(nxt, 3); }
      if (kt + 2 < NKT) { ALOAD(kt + 2, 2); ALOAD(kt + 2, 3); }
    } else {
      if (hn) { STGA(nxt, kt + 1, 1); STGA(nxt, kt + 1, 3); }
    }
    QUAD(3);
  }
#undef STGA
#undef STGB
#undef ALOAD
#undef AWRITE
#undef QUAD

  // ---- epilogue via LDS: swizzled scatter, then coalesced 16B stores ----
  asm volatile("s_waitcnt lgkmcnt(0) vmcnt(0)" ::: "memory");
  __builtin_amdgcn_s_barrier();                   // all waves done with stage LDS

  const int q4 = (l >> 4) * 4;
  float bvj[4];
#pragma unroll
  for (int jn = 0; jn < 4; ++jn) {
    const int col = wn * 64 + jn * 16 + r;
    bvj[jn] = bias ? bias[bn * 256 + col] : 0.f;
  }
#pragma unroll
  for (int i = 0; i < 8; ++i) {
#pragma unroll
    for (int jn = 0; jn < 4; ++jn) {
      const int col = wn * 64 + jn * 16 + r;
      const int chunk = col >> 3;
#pragma unroll
      for (int q = 0; q < 4; ++q) {
        const int rowl = wm * 128 + i * 16 + q4 + q;
        const int pch = chunk ^ (rowl & 7);
        smem[rowl * 256 + pch * 8 + (col & 7)] = f2bf(acc[i][jn][q] + bvj[jn]);
      }
    }
  }
  __builtin_amdgcn_s_barrier();

  const int rrow0 = t >> 5;                       // 0..15
  const int rch = t & 31;                         // logical 16B chunk
#pragma unroll
  for (int p = 0; p < 16; ++p) {
    const int rowl = p * 16 + rrow0;
    const int pch = rch ^ (rowl & 7);
    u16x8 vv = *(const u16x8*)&smem[rowl * 256 + pch * 8];
    const size_t grow = (size_t)(bm * 256 + rowl);
    *(u16x8*)&C[grow * N + bn * 256 + rch * 8] = vv;
  }
}

// ---------------------------------------------------------------------------
// Scan kernels. lin[row, 2048] (bf16): [theta | retain_logit | inp_r | inp_i]
// cum_mag as running product (== exp(cumsum(log(clip(rt,1e-6)))) within fp32
// noise); the 1e-8 clip on the inverse is preserved exactly.
// ---------------------------------------------------------------------------
__global__ __launch_bounds__(256) void scan_k1(const ushort* __restrict__ lin,
                                               float4* __restrict__ agg) {
  int bd = blockIdx.x * 256 + threadIdx.x;    // 0..2047  (b*512 + d)
  int c  = blockIdx.y;                         // 0..127
  int b  = bd >> 9, d = bd & 511;
  const ushort* base = lin + ((size_t)b * 4096 + (size_t)c * 32) * 2048;
  float cth = 0.f, cbr = 0.f, cbi = 0.f;
  float cm = 1.f, cs = 1.f, sn = 0.f;
#pragma unroll 4
  for (int t = 0; t < 32; ++t) {
    const ushort* row = base + (size_t)t * 2048;
    float th = bf2f(row[d]);
    float z  = bf2f(row[512 + d]);
    float ir = bf2f(row[1024 + d]);
    float ii = bf2f(row[1536 + d]);
    float rt = __fdividef(1.f, 1.f + __expf(-z));
    cm *= fmaxf(rt, 1e-6f);
    cth += th;
    float s_, c_;
    __sincosf(cth, &s_, &c_);
    float im = __fdividef(1.f, fmaxf(cm, 1e-8f));
    float invr = im * c_, invi = -im * s_;
    float drive = 1.f - rt;
    float br_ = drive * ir, bi_ = drive * ii;
    cbr += invr * br_ - invi * bi_;
    cbi += invr * bi_ + invi * br_;
    cs = c_; sn = s_;
  }
  agg[(size_t)c * 2048 + bd] = make_float4(cm * cs, cm * sn, cbr, cbi);
}

__global__ __launch_bounds__(256) void scan_k2(const float4* __restrict__ agg,
                                               float2* __restrict__ h0) {
  int bd = blockIdx.x * 256 + threadIdx.x;    // 2048 threads
  float hr = 0.f, hi = 0.f;
  for (int cg = 0; cg < 16; ++cg) {
    float4 a[8];
#pragma unroll
    for (int u = 0; u < 8; ++u) a[u] = agg[(size_t)(cg * 8 + u) * 2048 + bd];
#pragma unroll
    for (int u = 0; u < 8; ++u) {
      h0[(size_t)(cg * 8 + u) * 2048 + bd] = make_float2(hr, hi);
      float tr = hr + a[u].z, ti = hi + a[u].w;
      hr = a[u].x * tr - a[u].y * ti;
      hi = a[u].x * ti + a[u].y * tr;
    }
  }
}

__global__ __launch_bounds__(256) void scan_k3(const ushort* __restrict__ lin,
                                               const float2* __restrict__ h0,
                                               ushort* __restrict__ outb) {
  int bd = blockIdx.x * 256 + threadIdx.x;
  int c  = blockIdx.y;
  int b  = bd >> 9, d = bd & 511;
  const ushort* base = lin + ((size_t)b * 4096 + (size_t)c * 32) * 2048;
  float2 h = h0[(size_t)c * 2048 + bd];
  float cth = 0.f, cbr = 0.f, cbi = 0.f, cm = 1.f;
#pragma unroll 4
  for (int t = 0; t < 32; ++t) {
    const ushort* row = base + (size_t)t * 2048;
    float th = bf2f(row[d]);
    float z  = bf2f(row[512 + d]);
    float ir = bf2f(row[1024 + d]);
    float ii = bf2f(row[1536 + d]);
    float rt = __fdividef(1.f, 1.f + __expf(-z));
    cm *= fmaxf(rt, 1e-6f);
    cth += th;
    float s_, c_;
    __sincosf(cth, &s_, &c_);
    float im = __fdividef(1.f, fmaxf(cm, 1e-8f));
    float invr = im * c_, invi = -im * s_;
    float drive = 1.f - rt;
    float br_ = drive * ir, bi_ = drive * ii;
    cbr += invr * br_ - invi * bi_;
    cbi += invr * bi_ + invi * br_;
    float ar = cm * c_, ai = cm * s_;
    float tr = h.x + cbr, ti = h.y + cbi;
    float orr = ar * tr - ai * ti;
    float oii = ar * ti + ai * tr;
    size_t rowo = ((size_t)b * 4096 + (size_t)c * 32 + t) * 1024;
    outb[rowo + d] = f2bf(orr);
    outb[rowo + 512 + d] = f2bf(oii);
  }
}

// ---------------------------------------------------------------------------
// LayerNorm, one WAVE per row (4 rows/block). y = yb(bf16) + x(f32 residual).
// ---------------------------------------------------------------------------
__global__ __launch_bounds__(256) void ln_k(const ushort* __restrict__ yb,
                                            const float* __restrict__ x,
                                            const float* __restrict__ gamma,
                                            const float* __restrict__ beta,
                                            float* __restrict__ out) {
  const int lane = threadIdx.x & 63;
  const size_t row = (size_t)blockIdx.x * 4 + (threadIdx.x >> 6);
  const ushort* yr = yb + row * 1024;
  const float* xr = x + row * 1024;
  float v[4][4];
  float s = 0.f, s2 = 0.f;
#pragma unroll
  for (int q = 0; q < 4; ++q) {
    ushort4 uy = *(const ushort4*)(yr + q * 256 + lane * 4);
    float4 fx = *(const float4*)(xr + q * 256 + lane * 4);
    v[q][0] = bf2f(uy.x) + fx.x;
    v[q][1] = bf2f(uy.y) + fx.y;
    v[q][2] = bf2f(uy.z) + fx.z;
    v[q][3] = bf2f(uy.w) + fx.w;
#pragma unroll
    for (int j = 0; j < 4; ++j) { s += v[q][j]; s2 += v[q][j] * v[q][j]; }
  }
#pragma unroll
  for (int off = 32; off > 0; off >>= 1) {
    s  += __shfl_xor(s, off);
    s2 += __shfl_xor(s2, off);
  }
  const float mu = s * (1.f / 1024.f);
  const float rstd = rsqrtf(s2 * (1.f / 1024.f) - mu * mu + 1e-5f);
#pragma unroll
  for (int q = 0; q < 4; ++q) {
    float4 gv = *(const float4*)(gamma + q * 256 + lane * 4);
    float4 bv = *(const float4*)(beta + q * 256 + lane * 4);
    float4 o;
    o.x = (v[q][0] - mu) * rstd * gv.x + bv.x;
    o.y = (v[q][1] - mu) * rstd * gv.y + bv.y;
    o.z = (v[q][2] - mu) * rstd * gv.z + bv.z;
    o.w = (v[q][3] - mu) * rstd * gv.w + bv.w;
    *(float4*)(out + row * 1024 + q * 256 + lane * 4) = o;
  }
}

// ---------------------------------------------------------------------------
extern "C" void kernel_launch(void* const* d_in, const int* in_sizes, int n_in,
                              void* d_out, int out_size, void* d_ws, size_t ws_size,
                              hipStream_t stream) {
  (void)in_sizes; (void)n_in; (void)out_size; (void)ws_size;
  const float* x  = (const float*)d_in[0];
  const float* Wt = (const float*)d_in[1];
  const float* bt = (const float*)d_in[2];
  const float* Wr = (const float*)d_in[3];
  const float* br = (const float*)d_in[4];
  const float* Wi = (const float*)d_in[5];
  const float* bi = (const float*)d_in[6];
  const float* Wo = (const float*)d_in[7];
  const float* bo = (const float*)d_in[8];
  const float* gamma = (const float*)d_in[9];
  const float* beta  = (const float*)d_in[10];

  char* ws = (char*)d_ws;
  ushort* wcat_t = (ushort*)(ws);                      //  4 MiB: [2048][1024] bf16
  ushort* wo_t   = (ushort*)(ws + ((size_t)4  << 20)); //  2 MiB: [1024][1024] bf16
  float*  bcat   = (float*) (ws + ((size_t)6  << 20)); //  8 KiB
  float4* agg    = (float4*)(ws + ((size_t)8  << 20)); //  4 MiB: [128][2048]
  float2* h0     = (float2*)(ws + ((size_t)12 << 20)); //  2 MiB: [128][2048]
  ushort* outb   = (ushort*)(ws + ((size_t)48 << 20)); // 32 MiB: scan out bf16
  ushort* linb   = (ushort*)(ws + ((size_t)80 << 20)); // 64 MiB: lin bf16
  ushort* yb     = (ushort*)(ws + ((size_t)80 << 20)); // 32 MiB: y bf16 (overlays dead linb)

  // weight prep (fused) + bias pack
  tconv_all<<<dim3(32, 32, 4), dim3(32, 8), 0, stream>>>(Wt, Wr, Wi, Wo, wcat_t, wo_t);
  pack_bias<<<8, 256, 0, stream>>>(bt, br, bi, bcat);

  // lin(bf16) = x(f32, converted in-kernel) @ [Wt|Wr|Wi] + [bt|br|bi]
  gemm256<true><<<512, 512, 0, stream>>>(x, wcat_t, linb, bcat, 16384, 2048, 1024, 8);

  // chunked complex scan
  scan_k1<<<dim3(8, 128), 256, 0, stream>>>(linb, agg);
  scan_k2<<<8, 256, 0, stream>>>(agg, h0);
  scan_k3<<<dim3(8, 128), 256, 0, stream>>>(linb, h0, outb);

  // yb(bf16) = out @ Wo + bo   (256 blocks, 1/CU)
  gemm256<false><<<256, 512, 0, stream>>>(outb, wo_t, yb, bo, 16384, 1024, 1024, 4);

  // layernorm(yb + x) -> d_out   (one wave per row, f32 residual)
  ln_k<<<4096, 256, 0, stream>>>(yb, x, gamma, beta, (float*)d_out);
}